// Round 2
// baseline (549.518 us; speedup 1.0000x reference)
//
#include <hip/hip_runtime.h>
#include <hip/hip_bf16.h>

// NestedFeedForward: x[16384,1024] fp32, w1[4096,1024], b1[4096], w2[1024,4096],
// b2[1024], token_mask[16384] in [0,4).
//   d(t) = 1024 >> (3 - mask[t]) = 128 << mask[t]
//   h = gelu_erf( mask_in(x) @ w1^T + b1 )        (hidden always full 4096)
//   y = mask_out( h @ w2^T + b2 )
// Round 1: expert-sorted tokens -> per-row-block uniform d. gemm1 trims K to
// blkmax (input features beyond d are zero), gemm2 skips N-blocks beyond blkmax
// (outputs are zero). ~2.13x FLOP reduction vs dense.

typedef __bf16 bf16x8 __attribute__((ext_vector_type(8)));
typedef float f32x4 __attribute__((ext_vector_type(4)));

#define M_TOK   16384
#define DIM     1024
#define HID     4096

__device__ inline unsigned short f2bf(float f) {
  unsigned int u = __float_as_uint(f);
  u += 0x7fffu + ((u >> 16) & 1u);      // RNE; inputs finite
  return (unsigned short)(u >> 16);
}

__device__ inline void async_copy16(const void* g, void* s) {
  __builtin_amdgcn_global_load_lds(
      (const __attribute__((address_space(1))) unsigned int*)g,
      (__attribute__((address_space(3))) unsigned int*)s,
      16, 0, 0);
}

// Stage a 128-row x 64-col bf16 tile (row-major global, leading dim LDK elems)
// into 16 KB of LDS. XOR-swizzle the eight 16B chunks of each 128B row by
// (row&7) so MFMA-fragment ds_read_b128s are 2-way (free, m136) not 8-way.
template<int LDK>
__device__ inline void stage_tile(const unsigned short* __restrict__ g,
                                  int row0, int k0, char* lds) {
  const char* gbase = (const char*)g;
  int tid = threadIdx.x;
#pragma unroll
  for (int i = 0; i < 4; ++i) {
    int q = i * 256 + tid;          // 1024 chunks of 16B
    int r = q >> 3;                 // tile row 0..127
    int c = q & 7;                  // LDS chunk within row
    int gc = c ^ (r & 7);           // swizzled source chunk
    const void* gp = gbase + ((size_t)(row0 + r) * LDK + (size_t)k0 + gc * 8) * 2;
    async_copy16(gp, lds + (size_t)q * 16);
  }
}

// ---------------- sort / metadata ----------------

__global__ void zero_meta_kernel(int* p) {
  if (threadIdx.x < 32) p[threadIdx.x] = 0;
}

__global__ void hist_kernel(const int* __restrict__ tm, int* __restrict__ cnt) {
  __shared__ int h[4];
  if (threadIdx.x < 4) h[threadIdx.x] = 0;
  __syncthreads();
  int t = blockIdx.x * 256 + threadIdx.x;
  atomicAdd(&h[tm[t]], 1);
  __syncthreads();
  if (threadIdx.x < 4) atomicAdd(&cnt[threadIdx.x], h[threadIdx.x]);
}

// single block, 128 threads: exclusive scan of 4 counts + per-row-block max-d.
// Sorted ascending by expert => d non-decreasing => block max = last row's d.
__global__ void scan_meta_kernel(const int* __restrict__ cnt,
                                 int* __restrict__ base,
                                 int* __restrict__ blkmax) {
  __shared__ int s[4];
  if (threadIdx.x == 0) {
    int b = 0;
    for (int e = 0; e < 4; ++e) { base[e] = b; s[e] = b; b += cnt[e]; }
  }
  __syncthreads();
  int i = threadIdx.x;              // row-block id, 0..127
  int last = i * 128 + 127;
  int e = 0;
  if (last >= s[1]) e = 1;
  if (last >= s[2]) e = 2;
  if (last >= s[3]) e = 3;
  blkmax[i] = 128 << e;
}

// pos within expert group via atomic ticket; order within group irrelevant
// (output is token-wise independent; blkmax depends only on counts).
__global__ void scatter_kernel(const int* __restrict__ tm,
                               const int* __restrict__ base,
                               int* __restrict__ cnt2,
                               int* __restrict__ rowtok) {
  int t = blockIdx.x * 256 + threadIdx.x;
  int e = tm[t];
  int pos = base[e] + atomicAdd(&cnt2[e], 1);
  rowtok[pos] = t | (e << 14);      // t fits 14 bits (16384)
}

// move meta out of the d_out region (about to be overwritten) into the xb
// region (dead after gemm1). Runs between gemm1 and gemm2.
__global__ void copy_meta_kernel(const int* __restrict__ src_blk,
                                 const int* __restrict__ src_rt,
                                 int* __restrict__ dst_blk,
                                 int* __restrict__ dst_rt) {
  int i = blockIdx.x * 256 + threadIdx.x;
  if (i < 128) dst_blk[i] = src_blk[i];
  dst_rt[i] = src_rt[i];
}

// ---------------- conversions ----------------

// gather x[t] -> xb[pos] (permuted), bf16, zeroing features >= d_in(t)
__global__ void cvt_x_kernel(const float* __restrict__ x,
                             const int* __restrict__ rowtok,
                             unsigned short* __restrict__ xb) {
  int pos = blockIdx.x;
  int meta = rowtok[pos];
  int t = meta & 0x3FFF;
  int din = 128 << (meta >> 14);
  int d = threadIdx.x * 4;
  float4 v = *(const float4*)(x + (size_t)t * DIM + d);
  ushort4 o;
  if (d < din) {                    // din multiple of 128 -> float4-uniform
    o.x = f2bf(v.x); o.y = f2bf(v.y); o.z = f2bf(v.z); o.w = f2bf(v.w);
  } else {
    o.x = 0; o.y = 0; o.z = 0; o.w = 0;
  }
  *(ushort4*)(xb + (size_t)pos * DIM + d) = o;
}

__global__ void cvt_w_kernel(const float* __restrict__ src,
                             unsigned short* __restrict__ dst) {
  int i = (blockIdx.x * 256 + threadIdx.x) * 4;   // grid sized exactly
  float4 v = *(const float4*)(src + i);
  ushort4 o;
  o.x = f2bf(v.x); o.y = f2bf(v.y); o.z = f2bf(v.z); o.w = f2bf(v.w);
  *(ushort4*)(dst + i) = o;
}

// ---- GEMM1: hb[pos,f] = gelu( sum_d xb[pos,d]*w1b[f,d] + b1[f] ), bf16 out ----
// K-loop trimmed to blkmax[bx]; rows with smaller d_in have zero-padded xb.
__global__ __launch_bounds__(256) void gemm1_kernel(
    const unsigned short* __restrict__ A,   // xb [16384,1024] bf16 (permuted)
    const unsigned short* __restrict__ B,   // w1b [4096,1024] bf16
    const float* __restrict__ bias,         // b1 [4096]
    const int* __restrict__ kmaxs,          // [128]
    unsigned short* __restrict__ H)         // hb [16384,4096] bf16 (permuted)
{
  constexpr int K = DIM, N = HID;
  __shared__ char smem[32768];
  char* As = smem;
  char* Bs = smem + 16384;
  int tid = threadIdx.x;
  int lane = tid & 63, quad = lane >> 4, l15 = lane & 15;
  int wave = tid >> 6, wm = wave & 1, wn = wave >> 1;
  int row0 = blockIdx.x * 128, col0 = blockIdx.y * 128;
  int kmax = kmaxs[blockIdx.x];

  f32x4 acc[4][4] = {};

  for (int k0 = 0; k0 < kmax; k0 += 64) {
    __syncthreads();
    stage_tile<K>(A, row0, k0, As);
    stage_tile<K>(B, col0, k0, Bs);
    __syncthreads();
#pragma unroll
    for (int kk = 0; kk < 2; ++kk) {
      bf16x8 af[4], bg[4];
#pragma unroll
      for (int mt = 0; mt < 4; ++mt) {
        int m = wm * 64 + mt * 16 + l15;
        int ch = (kk * 4 + quad) ^ (m & 7);
        af[mt] = *(const bf16x8*)(As + m * 128 + ch * 16);
      }
#pragma unroll
      for (int nt = 0; nt < 4; ++nt) {
        int n = wn * 64 + nt * 16 + l15;
        int ch = (kk * 4 + quad) ^ (n & 7);
        bg[nt] = *(const bf16x8*)(Bs + n * 128 + ch * 16);
      }
#pragma unroll
      for (int mt = 0; mt < 4; ++mt)
#pragma unroll
        for (int nt = 0; nt < 4; ++nt)
          acc[mt][nt] = __builtin_amdgcn_mfma_f32_16x16x32_bf16(
              af[mt], bg[nt], acc[mt][nt], 0, 0, 0);
    }
  }

  // C/D layout: col=lane&15 (N), row=quad*4+reg (M)
  int t_base = row0 + wm * 64;
  int f_base = col0 + wn * 64;
#pragma unroll
  for (int nt = 0; nt < 4; ++nt) {
    int f = f_base + nt * 16 + l15;
    float bv = bias[f];
#pragma unroll
    for (int mt = 0; mt < 4; ++mt) {
#pragma unroll
      for (int r = 0; r < 4; ++r) {
        int t = t_base + mt * 16 + quad * 4 + r;
        float v = acc[mt][nt][r] + bv;
        v = 0.5f * v * (1.0f + erff(v * 0.7071067811865475f));  // exact-erf GELU
        H[(size_t)t * N + f] = f2bf(v);
      }
    }
  }
}

// ---- GEMM2: out[t,d] = (d < dout(t)) ? sum_f hb[pos,f]*w2b[d,f] + b2[d] : 0 ----
// col-blocks with col0 >= blkmax store zeros and skip the K loop entirely.
__global__ __launch_bounds__(256) void gemm2_kernel(
    const unsigned short* __restrict__ A,   // hb [16384,4096] bf16 (permuted)
    const unsigned short* __restrict__ B,   // w2b [1024,4096] bf16
    const float* __restrict__ bias,         // b2 [1024]
    const int* __restrict__ blkmax,         // [128] (xb-region copy)
    const int* __restrict__ rowtok,         // [16384] packed t | (e<<14)
    float* __restrict__ out)                // [16384,1024] fp32
{
  constexpr int K = HID, N = DIM;
  __shared__ char smem[32768];
  char* As = smem;
  char* Bs = smem + 16384;
  int tid = threadIdx.x;
  int lane = tid & 63, quad = lane >> 4, l15 = lane & 15;
  int wave = tid >> 6, wm = wave & 1, wn = wave >> 1;
  int row0 = blockIdx.x * 128, col0 = blockIdx.y * 128;
  int bmax = blkmax[blockIdx.x];

  int p_base = row0 + wm * 64;
  int d_base = col0 + wn * 64;

  if (col0 >= bmax) {
    // d >= blkmax >= d_out(t) for every row in this block -> all zeros.
#pragma unroll
    for (int mt = 0; mt < 4; ++mt) {
#pragma unroll
      for (int r = 0; r < 4; ++r) {
        int t = rowtok[p_base + mt * 16 + quad * 4 + r] & 0x3FFF;
#pragma unroll
        for (int nt = 0; nt < 4; ++nt) {
          int d = d_base + nt * 16 + l15;
          out[(size_t)t * N + d] = 0.0f;
        }
      }
    }
    return;
  }

  f32x4 acc[4][4] = {};

  for (int k0 = 0; k0 < K; k0 += 64) {
    __syncthreads();
    stage_tile<K>(A, row0, k0, As);
    stage_tile<K>(B, col0, k0, Bs);
    __syncthreads();
#pragma unroll
    for (int kk = 0; kk < 2; ++kk) {
      bf16x8 af[4], bg[4];
#pragma unroll
      for (int mt = 0; mt < 4; ++mt) {
        int m = wm * 64 + mt * 16 + l15;
        int ch = (kk * 4 + quad) ^ (m & 7);
        af[mt] = *(const bf16x8*)(As + m * 128 + ch * 16);
      }
#pragma unroll
      for (int nt = 0; nt < 4; ++nt) {
        int n = wn * 64 + nt * 16 + l15;
        int ch = (kk * 4 + quad) ^ (n & 7);
        bg[nt] = *(const bf16x8*)(Bs + n * 128 + ch * 16);
      }
#pragma unroll
      for (int mt = 0; mt < 4; ++mt)
#pragma unroll
        for (int nt = 0; nt < 4; ++nt)
          acc[mt][nt] = __builtin_amdgcn_mfma_f32_16x16x32_bf16(
              af[mt], bg[nt], acc[mt][nt], 0, 0, 0);
    }
  }

#pragma unroll
  for (int mt = 0; mt < 4; ++mt) {
#pragma unroll
    for (int r = 0; r < 4; ++r) {
      int meta = rowtok[p_base + mt * 16 + quad * 4 + r];
      int t = meta & 0x3FFF;
      int dout = 128 << (meta >> 14);
#pragma unroll
      for (int nt = 0; nt < 4; ++nt) {
        int d = d_base + nt * 16 + l15;
        float v = acc[mt][nt][r] + bias[d];
        out[(size_t)t * N + d] = (d < dout) ? v : 0.0f;
      }
    }
  }
}

extern "C" void kernel_launch(void* const* d_in, const int* in_sizes, int n_in,
                              void* d_out, int out_size, void* d_ws, size_t ws_size,
                              hipStream_t stream) {
  const float* x  = (const float*)d_in[0];
  const float* w1 = (const float*)d_in[1];
  const float* b1 = (const float*)d_in[2];
  const float* w2 = (const float*)d_in[3];
  const float* b2 = (const float*)d_in[4];
  const int*   tm = (const int*)d_in[5];
  float* out = (float*)d_out;

  char* ws = (char*)d_ws;
  unsigned short* xb  = (unsigned short*)(ws);              // 32 MB
  unsigned short* w1b = (unsigned short*)(ws + 33554432);   //  8 MB
  unsigned short* w2b = (unsigned short*)(ws + 41943040);   //  8 MB
  unsigned short* hb  = (unsigned short*)(ws + 50331648);   // 128 MB (total 176 MB)

  // Sort metadata lives in the d_out region until gemm2 needs to write out.
  int* o      = (int*)d_out;
  int* cnt    = o;            // [4]
  int* cnt2   = o + 4;        // [4]
  int* base   = o + 16;       // [4]
  int* blkmax = o + 64;       // [128]
  int* rowtok = o + 256;      // [16384]
  // Final meta home: start of xb region (dead after gemm1).
  int* blkmax2 = (int*)ws;          // [128]
  int* rowtok2 = (int*)ws + 256;    // [16384]

  zero_meta_kernel<<<1, 64, 0, stream>>>(o);
  hist_kernel<<<M_TOK / 256, 256, 0, stream>>>(tm, cnt);
  scan_meta_kernel<<<1, 128, 0, stream>>>(cnt, base, blkmax);
  scatter_kernel<<<M_TOK / 256, 256, 0, stream>>>(tm, base, cnt2, rowtok);

  cvt_x_kernel<<<M_TOK, 256, 0, stream>>>(x, rowtok, xb);
  cvt_w_kernel<<<(HID * DIM) / 1024, 256, 0, stream>>>(w1, w1b);
  cvt_w_kernel<<<(DIM * HID) / 1024, 256, 0, stream>>>(w2, w2b);

  gemm1_kernel<<<dim3(M_TOK / 128, HID / 128), 256, 0, stream>>>(xb, w1b, b1, blkmax, hb);

  copy_meta_kernel<<<M_TOK / 256, 256, 0, stream>>>(blkmax, rowtok, blkmax2, rowtok2);

  gemm2_kernel<<<dim3(M_TOK / 128, DIM / 128), 256, 0, stream>>>(hb, w2b, b2, blkmax2, rowtok2, out);
}

// Round 3
// 490.337 us; speedup vs baseline: 1.1207x; 1.1207x over previous
//
#include <hip/hip_runtime.h>
#include <hip/hip_bf16.h>

// NestedFeedForward: x[16384,1024] fp32, w1[4096,1024], b1[4096], w2[1024,4096],
// b2[1024], token_mask[16384] in [0,4).
//   d(t) = 128 << mask[t]
//   h = gelu_erf( mask_in(x) @ w1^T + b1 )        (hidden always full 4096)
//   y = mask_out( h @ w2^T + b2 )
// Round 2: fast-poly erf epilogue (A&S 7.1.26, |err|<2.5e-5), simplified
// swizzle addressing, gemm2 via compact compute-block map + float4 zero
// prefill of out (kills scattered zero-stores and balances dispatch).

typedef __bf16 bf16x8 __attribute__((ext_vector_type(8)));
typedef float f32x4 __attribute__((ext_vector_type(4)));

#define M_TOK   16384
#define DIM     1024
#define HID     4096

// meta layout (ints): [0..3] cnt, [4..7] cnt2, [16..19] base, [31] T,
// [64..191] blkmax, [192..1215] map, [1280..17663] rowtok.  17664 ints total.
#define META_T     31
#define META_BLK   64
#define META_MAP   192
#define META_RT    1280
#define META_INTS  17664

__device__ inline unsigned short f2bf(float f) {
  unsigned int u = __float_as_uint(f);
  u += 0x7fffu + ((u >> 16) & 1u);      // RNE; inputs finite
  return (unsigned short)(u >> 16);
}

// gelu with A&S 7.1.26 erf: abs err <= ~2.5e-5, branchless, ~14 VALU + exp
__device__ inline float gelu_f(float v) {
  float z = fabsf(v) * 0.7071067811865475f;
  float t = __builtin_amdgcn_rcpf(fmaf(0.3275911f, z, 1.0f));
  float p = fmaf(t, 1.061405429f, -1.453152027f);
  p = fmaf(t, p, 1.421413741f);
  p = fmaf(t, p, -0.284496736f);
  p = fmaf(t, p, 0.254829592f);
  p = p * t;
  float E = __expf(-0.5f * v * v);       // e^{-z^2}
  float er = fmaf(-p, E, 1.0f);          // erf(z), z>=0
  er = copysignf(er, v);
  return 0.5f * v * (1.0f + er);
}

__device__ inline void async_copy16(const void* g, void* s) {
  __builtin_amdgcn_global_load_lds(
      (const __attribute__((address_space(1))) unsigned int*)g,
      (__attribute__((address_space(3))) unsigned int*)s,
      16, 0, 0);
}

// Stage a 128-row x 64-col bf16 tile into 16 KB LDS with XOR chunk swizzle.
template<int LDK>
__device__ inline void stage_tile(const unsigned short* __restrict__ g,
                                  int row0, int k0, char* lds) {
  const char* gbase = (const char*)g;
  int tid = threadIdx.x;
#pragma unroll
  for (int i = 0; i < 4; ++i) {
    int q = i * 256 + tid;          // 1024 chunks of 16B
    int r = q >> 3;                 // tile row 0..127
    int c = q & 7;                  // LDS chunk within row
    int gc = c ^ (r & 7);           // swizzled source chunk
    const void* gp = gbase + ((size_t)(row0 + r) * LDK + (size_t)k0 + gc * 8) * 2;
    async_copy16(gp, lds + (size_t)q * 16);
  }
}

// ---------------- sort / metadata ----------------

__global__ void zero_meta_kernel(int* p) {
  if (threadIdx.x < 32) p[threadIdx.x] = 0;
}

__global__ void hist_kernel(const int* __restrict__ tm, int* __restrict__ cnt) {
  __shared__ int h[4];
  if (threadIdx.x < 4) h[threadIdx.x] = 0;
  __syncthreads();
  int t = blockIdx.x * 256 + threadIdx.x;
  atomicAdd(&h[tm[t]], 1);
  __syncthreads();
  if (threadIdx.x < 4) atomicAdd(&cnt[threadIdx.x], h[threadIdx.x]);
}

// single block, 128 threads: exclusive scan of 4 counts, per-row-block max-d,
// and compact compute-block map (row-major list of (rowblk,colblk) pairs).
__global__ void scan_meta_kernel(int* __restrict__ meta) {
  const int* cnt = meta;
  int* base   = meta + 16;
  int* blkmax = meta + META_BLK;
  int* map    = meta + META_MAP;
  __shared__ int s[4];
  __shared__ int cb[128];
  __shared__ int pfx[128];
  if (threadIdx.x == 0) {
    int b = 0;
    for (int e = 0; e < 4; ++e) { base[e] = b; s[e] = b; b += cnt[e]; }
  }
  __syncthreads();
  int i = threadIdx.x;              // row-block id 0..127
  int last = i * 128 + 127;
  int e = 0;
  if (last >= s[1]) e = 1;
  if (last >= s[2]) e = 2;
  if (last >= s[3]) e = 3;
  blkmax[i] = 128 << e;             // K-trim for gemm1
  cb[i] = 1 << e;                   // compute col-blocks for gemm2
  __syncthreads();
  if (threadIdx.x == 0) {
    int acc = 0;
    for (int j = 0; j < 128; ++j) { int c = cb[j]; cb[j] = acc; acc += c; }
    meta[META_T] = acc;             // T = total compute blocks (<=1024)
    for (int j = 0; j < 128; ++j) pfx[j] = cb[j];
  }
  __syncthreads();
  int p = pfx[i];
  int n = (i == 127) ? (meta[META_T] - p) : (pfx[i + 1] - p);
  for (int j = 0; j < n; ++j) map[p + j] = i * 8 + j;
}

// pos within expert group via atomic ticket; order within group irrelevant.
__global__ void scatter_kernel(const int* __restrict__ tm,
                               int* __restrict__ meta) {
  const int* base = meta + 16;
  int* cnt2 = meta + 4;
  int* rowtok = meta + META_RT;
  int t = blockIdx.x * 256 + threadIdx.x;
  int e = tm[t];
  int pos = base[e] + atomicAdd(&cnt2[e], 1);
  rowtok[pos] = t | (e << 14);      // t fits 14 bits
}

// move meta out of d_out (about to be zero-filled) into xb region (dead
// after gemm1).
__global__ void copy_meta_kernel(const int* __restrict__ src, int* __restrict__ dst) {
  int i = blockIdx.x * 256 + threadIdx.x;
  if (i < META_INTS) dst[i] = src[i];
}

__global__ void zero_out_kernel(float4* __restrict__ out) {
  out[(size_t)blockIdx.x * 256 + threadIdx.x] = make_float4(0.f, 0.f, 0.f, 0.f);
}

// ---------------- conversions ----------------

__global__ void cvt_x_kernel(const float* __restrict__ x,
                             const int* __restrict__ meta,
                             unsigned short* __restrict__ xb) {
  const int* rowtok = meta + META_RT;
  int pos = blockIdx.x;
  int mt = rowtok[pos];
  int t = mt & 0x3FFF;
  int din = 128 << (mt >> 14);
  int d = threadIdx.x * 4;
  float4 v = *(const float4*)(x + (size_t)t * DIM + d);
  ushort4 o;
  if (d < din) {                    // din multiple of 128 -> float4-uniform
    o.x = f2bf(v.x); o.y = f2bf(v.y); o.z = f2bf(v.z); o.w = f2bf(v.w);
  } else {
    o.x = 0; o.y = 0; o.z = 0; o.w = 0;
  }
  *(ushort4*)(xb + (size_t)pos * DIM + d) = o;
}

__global__ void cvt_w_kernel(const float* __restrict__ src,
                             unsigned short* __restrict__ dst) {
  int i = (blockIdx.x * 256 + threadIdx.x) * 4;
  float4 v = *(const float4*)(src + i);
  ushort4 o;
  o.x = f2bf(v.x); o.y = f2bf(v.y); o.z = f2bf(v.z); o.w = f2bf(v.w);
  *(ushort4*)(dst + i) = o;
}

// ---- GEMM1: hb[pos,f] = gelu( xb[pos,:] . w1b[f,:] + b1[f] ), bf16 out ----
__global__ __launch_bounds__(256) void gemm1_kernel(
    const unsigned short* __restrict__ A,   // xb [16384,1024] bf16 (permuted)
    const unsigned short* __restrict__ B,   // w1b [4096,1024] bf16
    const float* __restrict__ bias,         // b1 [4096]
    const int* __restrict__ meta,           // blkmax at META_BLK
    unsigned short* __restrict__ H)         // hb [16384,4096] bf16 (permuted)
{
  constexpr int K = DIM, N = HID;
  __shared__ char smem[32768];
  char* As = smem;
  char* Bs = smem + 16384;
  int tid = threadIdx.x;
  int lane = tid & 63, quad = lane >> 4, l15 = lane & 15;
  int wave = tid >> 6, wm = wave & 1, wn = wave >> 1;
  int row0 = blockIdx.x * 128, col0 = blockIdx.y * 128;
  int kmax = meta[META_BLK + blockIdx.x];

  // swizzled chunk byte-offset; kk toggles bit 6
  int chb = (quad ^ (l15 & 7)) << 4;

  f32x4 acc[4][4] = {};

  for (int k0 = 0; k0 < kmax; k0 += 64) {
    __syncthreads();
    stage_tile<K>(A, row0, k0, As);
    stage_tile<K>(B, col0, k0, Bs);
    __syncthreads();
#pragma unroll
    for (int kk = 0; kk < 2; ++kk) {
      int xo = chb ^ (kk << 6);
      bf16x8 af[4], bg[4];
#pragma unroll
      for (int mt = 0; mt < 4; ++mt)
        af[mt] = *(const bf16x8*)(As + (wm * 64 + mt * 16 + l15) * 128 + xo);
#pragma unroll
      for (int nt = 0; nt < 4; ++nt)
        bg[nt] = *(const bf16x8*)(Bs + (wn * 64 + nt * 16 + l15) * 128 + xo);
#pragma unroll
      for (int mt = 0; mt < 4; ++mt)
#pragma unroll
        for (int nt = 0; nt < 4; ++nt)
          acc[mt][nt] = __builtin_amdgcn_mfma_f32_16x16x32_bf16(
              af[mt], bg[nt], acc[mt][nt], 0, 0, 0);
    }
  }

  // C/D layout: col=lane&15 (N), row=quad*4+reg (M)
  int t_base = row0 + wm * 64;
  int f_base = col0 + wn * 64;
#pragma unroll
  for (int nt = 0; nt < 4; ++nt) {
    int f = f_base + nt * 16 + l15;
    float bv = bias[f];
#pragma unroll
    for (int mt = 0; mt < 4; ++mt) {
#pragma unroll
      for (int r = 0; r < 4; ++r) {
        int t = t_base + mt * 16 + quad * 4 + r;
        float v = gelu_f(acc[mt][nt][r] + bv);
        H[(size_t)t * N + f] = f2bf(v);
      }
    }
  }
}

// ---- GEMM2: out[t,d] += hb[pos,:] . w2b[d,:] + b2[d]  (compute blocks only) ----
__global__ __launch_bounds__(256) void gemm2_kernel(
    const unsigned short* __restrict__ A,   // hb [16384,4096] bf16 (permuted)
    const unsigned short* __restrict__ B,   // w2b [1024,4096] bf16
    const float* __restrict__ bias,         // b2 [1024]
    const int* __restrict__ meta,           // ws copy: T, map, rowtok
    float* __restrict__ out)                // [16384,1024] fp32 (pre-zeroed)
{
  constexpr int K = HID, N = DIM;
  int T = meta[META_T];
  int b = blockIdx.x;
  if (b >= T) return;                       // zero region handled by prefill
  int mp = meta[META_MAP + b];
  int row0 = (mp >> 3) * 128, col0 = (mp & 7) * 128;
  const int* rowtok = meta + META_RT;

  __shared__ char smem[32768];
  char* As = smem;
  char* Bs = smem + 16384;
  int tid = threadIdx.x;
  int lane = tid & 63, quad = lane >> 4, l15 = lane & 15;
  int wave = tid >> 6, wm = wave & 1, wn = wave >> 1;
  int chb = (quad ^ (l15 & 7)) << 4;

  f32x4 acc[4][4] = {};

  for (int k0 = 0; k0 < K; k0 += 64) {
    __syncthreads();
    stage_tile<K>(A, row0, k0, As);
    stage_tile<K>(B, col0, k0, Bs);
    __syncthreads();
#pragma unroll
    for (int kk = 0; kk < 2; ++kk) {
      int xo = chb ^ (kk << 6);
      bf16x8 af[4], bg[4];
#pragma unroll
      for (int mt = 0; mt < 4; ++mt)
        af[mt] = *(const bf16x8*)(As + (wm * 64 + mt * 16 + l15) * 128 + xo);
#pragma unroll
      for (int nt = 0; nt < 4; ++nt)
        bg[nt] = *(const bf16x8*)(Bs + (wn * 64 + nt * 16 + l15) * 128 + xo);
#pragma unroll
      for (int mt = 0; mt < 4; ++mt)
#pragma unroll
        for (int nt = 0; nt < 4; ++nt)
          acc[mt][nt] = __builtin_amdgcn_mfma_f32_16x16x32_bf16(
              af[mt], bg[nt], acc[mt][nt], 0, 0, 0);
    }
  }

  int p_base = row0 + wm * 64;
  int d_base = col0 + wn * 64;
#pragma unroll
  for (int mt = 0; mt < 4; ++mt) {
#pragma unroll
    for (int r = 0; r < 4; ++r) {
      int m2 = rowtok[p_base + mt * 16 + quad * 4 + r];
      int t = m2 & 0x3FFF;
      int dout = 128 << (m2 >> 14);
#pragma unroll
      for (int nt = 0; nt < 4; ++nt) {
        int d = d_base + nt * 16 + l15;
        if (d < dout)                        // prefill already wrote zeros
          out[(size_t)t * N + d] = acc[mt][nt][r] + bias[d];
      }
    }
  }
}

extern "C" void kernel_launch(void* const* d_in, const int* in_sizes, int n_in,
                              void* d_out, int out_size, void* d_ws, size_t ws_size,
                              hipStream_t stream) {
  const float* x  = (const float*)d_in[0];
  const float* w1 = (const float*)d_in[1];
  const float* b1 = (const float*)d_in[2];
  const float* w2 = (const float*)d_in[3];
  const float* b2 = (const float*)d_in[4];
  const int*   tm = (const int*)d_in[5];
  float* out = (float*)d_out;

  char* ws = (char*)d_ws;
  unsigned short* xb  = (unsigned short*)(ws);              // 32 MB
  unsigned short* w1b = (unsigned short*)(ws + 33554432);   //  8 MB
  unsigned short* w2b = (unsigned short*)(ws + 41943040);   //  8 MB
  unsigned short* hb  = (unsigned short*)(ws + 50331648);   // 128 MB (total 176 MB)

  int* metaO = (int*)d_out;    // meta lives in d_out until zero_out
  int* metaW = (int*)ws;       // post-gemm1 home (start of dead xb region)

  zero_meta_kernel<<<1, 64, 0, stream>>>(metaO);
  hist_kernel<<<M_TOK / 256, 256, 0, stream>>>(tm, metaO);
  scan_meta_kernel<<<1, 128, 0, stream>>>(metaO);
  scatter_kernel<<<M_TOK / 256, 256, 0, stream>>>(tm, metaO);

  cvt_x_kernel<<<M_TOK, 256, 0, stream>>>(x, metaO, xb);
  cvt_w_kernel<<<(HID * DIM) / 1024, 256, 0, stream>>>(w1, w1b);
  cvt_w_kernel<<<(DIM * HID) / 1024, 256, 0, stream>>>(w2, w2b);

  gemm1_kernel<<<dim3(M_TOK / 128, HID / 128), 256, 0, stream>>>(xb, w1b, b1, metaO, hb);

  copy_meta_kernel<<<(META_INTS + 255) / 256, 256, 0, stream>>>(metaO, metaW);
  zero_out_kernel<<<(M_TOK * DIM) / 1024, 256, 0, stream>>>((float4*)out);

  gemm2_kernel<<<1024, 256, 0, stream>>>(hb, w2b, b2, metaW, out);
}

// Round 4
// 370.964 us; speedup vs baseline: 1.4813x; 1.3218x over previous
//
#include <hip/hip_runtime.h>
#include <hip/hip_bf16.h>

// NestedFeedForward: x[16384,1024] fp32, w1[4096,1024], b1[4096], w2[1024,4096],
// b2[1024], token_mask[16384] in [0,4).   d(t) = 128 << mask[t]
//   h = gelu_erf( mask_in(x) @ w1^T + b1 )   (hidden always full 4096)
//   y = mask_out( h @ w2^T + b2 )
// Round 3: 4 launches total (fused sort, fused prep, gemm1, gemm2-with-zeros).
// gemm1 epilogue assembles bf16 tile in LDS (swizzled, conflict-free) for
// coalesced 16B stores. Meta lives at ws+0; no d_out scratch, no copies.

typedef __bf16 bf16x8 __attribute__((ext_vector_type(8)));
typedef float f32x4 __attribute__((ext_vector_type(4)));

#define M_TOK   16384
#define DIM     1024
#define HID     4096

// meta (ints at ws+0): [31] T, [64..191] blkmax, [192..1215] map (compute
// blocks first, then zero blocks; 1024 total), [1280..17663] rowtok.
#define META_T     31
#define META_BLK   64
#define META_MAP   192
#define META_RT    1280

__device__ inline unsigned short f2bf(float f) {
  unsigned int u = __float_as_uint(f);
  u += 0x7fffu + ((u >> 16) & 1u);      // RNE; inputs finite
  return (unsigned short)(u >> 16);
}

// gelu with A&S 7.1.26 erf: abs err <= ~2.5e-5 (proven absmax 0.0039 total)
__device__ inline float gelu_f(float v) {
  float z = fabsf(v) * 0.7071067811865475f;
  float t = __builtin_amdgcn_rcpf(fmaf(0.3275911f, z, 1.0f));
  float p = fmaf(t, 1.061405429f, -1.453152027f);
  p = fmaf(t, p, 1.421413741f);
  p = fmaf(t, p, -0.284496736f);
  p = fmaf(t, p, 0.254829592f);
  p = p * t;
  float E = __expf(-0.5f * v * v);
  float er = fmaf(-p, E, 1.0f);
  er = copysignf(er, v);
  return 0.5f * v * (1.0f + er);
}

__device__ inline void async_copy16(const void* g, void* s) {
  __builtin_amdgcn_global_load_lds(
      (const __attribute__((address_space(1))) unsigned int*)g,
      (__attribute__((address_space(3))) unsigned int*)s,
      16, 0, 0);
}

// Stage a 128-row x 64-col bf16 tile into 16 KB LDS with XOR chunk swizzle.
template<int LDK>
__device__ inline void stage_tile(const unsigned short* __restrict__ g,
                                  int row0, int k0, char* lds) {
  const char* gbase = (const char*)g;
  int tid = threadIdx.x;
#pragma unroll
  for (int i = 0; i < 4; ++i) {
    int q = i * 256 + tid;          // 1024 chunks of 16B
    int r = q >> 3;                 // tile row 0..127
    int c = q & 7;                  // LDS chunk within row
    int gc = c ^ (r & 7);           // swizzled source chunk
    const void* gp = gbase + ((size_t)(row0 + r) * LDK + (size_t)k0 + gc * 8) * 2;
    async_copy16(gp, lds + (size_t)q * 16);
  }
}

// ---------------- fused sort + metadata (single block) ----------------
// Per-thread histogram of 16 tokens -> Hillis-Steele scan over 1024 threads
// (per expert) -> deterministic scatter (no atomics) + blkmax/map build.
__global__ __launch_bounds__(1024) void sort_kernel(const int* __restrict__ tm,
                                                    int* __restrict__ meta) {
  __shared__ int cnt[1024][5];      // [5] pad: stride 5 dwords -> conflict-free
  __shared__ int sbase[5];
  __shared__ int cb[128];
  __shared__ int pfx[129];
  int tid = threadIdx.x;

  int c0 = 0, c1 = 0, c2 = 0, c3 = 0;
  unsigned int epack = 0;
  int4 tv[4];
#pragma unroll
  for (int j = 0; j < 4; ++j)
    tv[j] = *(const int4*)(tm + tid * 16 + j * 4);
#pragma unroll
  for (int j = 0; j < 4; ++j) {
    int e;
    e = tv[j].x; epack |= (unsigned)e << (2 * (4 * j + 0)); c0 += (e == 0); c1 += (e == 1); c2 += (e == 2); c3 += (e == 3);
    e = tv[j].y; epack |= (unsigned)e << (2 * (4 * j + 1)); c0 += (e == 0); c1 += (e == 1); c2 += (e == 2); c3 += (e == 3);
    e = tv[j].z; epack |= (unsigned)e << (2 * (4 * j + 2)); c0 += (e == 0); c1 += (e == 1); c2 += (e == 2); c3 += (e == 3);
    e = tv[j].w; epack |= (unsigned)e << (2 * (4 * j + 3)); c0 += (e == 0); c1 += (e == 1); c2 += (e == 2); c3 += (e == 3);
  }
  cnt[tid][0] = c0; cnt[tid][1] = c1; cnt[tid][2] = c2; cnt[tid][3] = c3;
  __syncthreads();
  // inclusive scan over tid, 4 lanes wide
  for (int s = 1; s < 1024; s <<= 1) {
    int v0 = 0, v1 = 0, v2 = 0, v3 = 0;
    if (tid >= s) {
      v0 = cnt[tid - s][0]; v1 = cnt[tid - s][1];
      v2 = cnt[tid - s][2]; v3 = cnt[tid - s][3];
    }
    __syncthreads();
    cnt[tid][0] += v0; cnt[tid][1] += v1; cnt[tid][2] += v2; cnt[tid][3] += v3;
    __syncthreads();
  }
  if (tid == 0) {
    int b = 0;
#pragma unroll
    for (int e = 0; e < 4; ++e) { sbase[e] = b; b += cnt[1023][e]; }
    sbase[4] = b;
  }
  __syncthreads();
  // scatter: thread's exclusive start per expert
  int off0 = sbase[0] + cnt[tid][0] - c0;
  int off1 = sbase[1] + cnt[tid][1] - c1;
  int off2 = sbase[2] + cnt[tid][2] - c2;
  int off3 = sbase[3] + cnt[tid][3] - c3;
  int* rowtok = meta + META_RT;
#pragma unroll
  for (int j = 0; j < 16; ++j) {
    int e = (epack >> (2 * j)) & 3;
    int t = tid * 16 + j;
    int pos = (e == 0) ? off0++ : (e == 1) ? off1++ : (e == 2) ? off2++ : off3++;
    rowtok[pos] = t | (e << 14);
  }
  // blkmax + compute/zero map
  if (tid < 128) {
    int last = tid * 128 + 127;
    int e = (last >= sbase[1]) + (last >= sbase[2]) + (last >= sbase[3]);
    meta[META_BLK + tid] = 128 << e;
    cb[tid] = 1 << e;
  }
  __syncthreads();
  if (tid == 0) {
    int acc = 0;
    for (int j = 0; j < 128; ++j) { pfx[j] = acc; acc += cb[j]; }
    pfx[128] = acc;
    meta[META_T] = acc;
  }
  __syncthreads();
  if (tid < 128) {
    int n = cb[tid];
    int p = pfx[tid];
    int* map = meta + META_MAP;
    for (int c = 0; c < n; ++c) map[p + c] = tid * 8 + c;
    int zp = pfx[128] + 8 * tid - pfx[tid];          // zeros before this rowblk
    for (int c = n; c < 8; ++c) map[zp + (c - n)] = tid * 8 + c;
  }
}

// ---------------- fused prep: cvt_x (permuted gather) + w1/w2 -> bf16 ------
__global__ void prep_kernel(const float* __restrict__ x,
                            const float* __restrict__ w1,
                            const float* __restrict__ w2,
                            const int* __restrict__ meta,
                            unsigned short* __restrict__ xb,
                            unsigned short* __restrict__ w1b,
                            unsigned short* __restrict__ w2b) {
  int b = blockIdx.x;
  int tid = threadIdx.x;
  if (b < M_TOK) {
    int mt = meta[META_RT + b];
    int t = mt & 0x3FFF;
    int din = 128 << (mt >> 14);
    int d = tid * 4;
    float4 v = *(const float4*)(x + (size_t)t * DIM + d);
    ushort4 o;
    if (d < din) {                  // din multiple of 128 -> float4-uniform
      o.x = f2bf(v.x); o.y = f2bf(v.y); o.z = f2bf(v.z); o.w = f2bf(v.w);
    } else {
      o.x = 0; o.y = 0; o.z = 0; o.w = 0;
    }
    *(ushort4*)(xb + (size_t)b * DIM + d) = o;
  } else {
    size_t i = (size_t)(b - M_TOK) * 1024 + tid * 4;   // 0 .. 8388607
    const float* src;
    unsigned short* dst;
    if (i < (size_t)HID * DIM) { src = w1; dst = w1b; }
    else { src = w2 - (size_t)HID * DIM; dst = w2b - (size_t)HID * DIM; }
    float4 v = *(const float4*)(src + i);
    ushort4 o;
    o.x = f2bf(v.x); o.y = f2bf(v.y); o.z = f2bf(v.z); o.w = f2bf(v.w);
    *(ushort4*)(dst + i) = o;
  }
}

// ---- GEMM1: hb[pos,f] = gelu( xb[pos,:] . w1b[f,:] + b1[f] ), bf16 out ----
__global__ __launch_bounds__(256) void gemm1_kernel(
    const unsigned short* __restrict__ A,   // xb [16384,1024] bf16 (permuted)
    const unsigned short* __restrict__ B,   // w1b [4096,1024] bf16
    const float* __restrict__ bias,         // b1 [4096]
    const int* __restrict__ meta,
    unsigned short* __restrict__ H)         // hb [16384,4096] bf16 (permuted)
{
  constexpr int K = DIM, N = HID;
  __shared__ char smem[32768];
  char* As = smem;
  char* Bs = smem + 16384;
  int tid = threadIdx.x;
  int lane = tid & 63, quad = lane >> 4, l15 = lane & 15;
  int wave = tid >> 6, wm = wave & 1, wn = wave >> 1;
  int row0 = blockIdx.x * 128, col0 = blockIdx.y * 128;
  int kmax = meta[META_BLK + blockIdx.x];

  int chb = (quad ^ (l15 & 7)) << 4;        // staging swizzle base

  f32x4 acc[4][4] = {};

  for (int k0 = 0; k0 < kmax; k0 += 64) {
    __syncthreads();
    stage_tile<K>(A, row0, k0, As);
    stage_tile<K>(B, col0, k0, Bs);
    __syncthreads();
#pragma unroll
    for (int kk = 0; kk < 2; ++kk) {
      int xo = chb ^ (kk << 6);
      bf16x8 af[4], bg[4];
#pragma unroll
      for (int mt = 0; mt < 4; ++mt)
        af[mt] = *(const bf16x8*)(As + (wm * 64 + mt * 16 + l15) * 128 + xo);
#pragma unroll
      for (int nt = 0; nt < 4; ++nt)
        bg[nt] = *(const bf16x8*)(Bs + (wn * 64 + nt * 16 + l15) * 128 + xo);
#pragma unroll
      for (int mt = 0; mt < 4; ++mt)
#pragma unroll
        for (int nt = 0; nt < 4; ++nt)
          acc[mt][nt] = __builtin_amdgcn_mfma_f32_16x16x32_bf16(
              af[mt], bg[nt], acc[mt][nt], 0, 0, 0);
    }
  }

  // Epilogue: gelu -> bf16 tile in LDS (32B-chunk XOR-quad swizzle,
  // conflict-free writes & reads), then coalesced 16B stores.
  // cell (t,f) at: t*256 + ((( (f*2)>>5 ) ^ ((t>>2)&3))<<5) + ((f*2)&31)
  __syncthreads();                          // staging reads done
  {
    int wb = (wm * 64 + quad * 4) * 256 + wn * 128 + (quad << 5) + l15 * 2;
#pragma unroll
    for (int nt = 0; nt < 4; ++nt) {
      int f = col0 + wn * 64 + nt * 16 + l15;
      float bv = bias[f];
      int xadr = wb ^ (nt << 5);            // bits5:6 = quad^nt
#pragma unroll
      for (int mt = 0; mt < 4; ++mt) {
#pragma unroll
        for (int r = 0; r < 4; ++r) {
          float v = gelu_f(acc[mt][nt][r] + bv);
          *(unsigned short*)(smem + xadr + mt * 4096 + r * 256) = f2bf(v);
        }
      }
    }
  }
  __syncthreads();
  {
    int row = tid >> 4;                     // 0..15
    int c = tid & 15;                       // 16B chunk within row
    int raddr = row * 256 + ((((c >> 1) ^ ((row >> 2) & 3))) << 5) + ((c & 1) << 4);
    const unsigned short* hbase = H;        // permuted-row output
    size_t gb = (size_t)(row0 + row) * N + col0 + c * 8;
#pragma unroll
    for (int i = 0; i < 8; ++i) {           // row += 16 each iter; swizzle invariant
      bf16x8 v = *(const bf16x8*)(smem + raddr + i * 4096);
      *(bf16x8*)(hbase + gb + (size_t)i * 16 * N) = v;
    }
  }
}

// ---- GEMM2: compute blocks b<T; zero blocks b>=T (coalesced float4) ----
__global__ __launch_bounds__(256) void gemm2_kernel(
    const unsigned short* __restrict__ A,   // hb [16384,4096] bf16 (permuted)
    const unsigned short* __restrict__ B,   // w2b [1024,4096] bf16
    const float* __restrict__ bias,         // b2 [1024]
    const int* __restrict__ meta,
    float* __restrict__ out)                // [16384,1024] fp32
{
  constexpr int K = HID, N = DIM;
  int T = meta[META_T];
  int b = blockIdx.x;
  int mp = meta[META_MAP + b];
  int row0 = (mp >> 3) * 128, col0 = (mp & 7) * 128;
  const int* rowtok = meta + META_RT;
  int tid = threadIdx.x;

  if (b >= T) {
    // every row in this block has dout <= col0: write zeros, coalesced
    float4 z = make_float4(0.f, 0.f, 0.f, 0.f);
#pragma unroll
    for (int i = 0; i < 16; ++i) {
      int idx = i * 256 + tid;              // 4096 float4s = 128x128 tile
      int r = idx >> 5;
      int col = (idx & 31) * 4;
      int t = rowtok[row0 + r] & 0x3FFF;
      *(float4*)(out + (size_t)t * N + col0 + col) = z;
    }
    return;
  }

  __shared__ char smem[32768];
  char* As = smem;
  char* Bs = smem + 16384;
  int lane = tid & 63, quad = lane >> 4, l15 = lane & 15;
  int wave = tid >> 6, wm = wave & 1, wn = wave >> 1;
  int chb = (quad ^ (l15 & 7)) << 4;

  f32x4 acc[4][4] = {};

  for (int k0 = 0; k0 < K; k0 += 64) {
    __syncthreads();
    stage_tile<K>(A, row0, k0, As);
    stage_tile<K>(B, col0, k0, Bs);
    __syncthreads();
#pragma unroll
    for (int kk = 0; kk < 2; ++kk) {
      int xo = chb ^ (kk << 6);
      bf16x8 af[4], bg[4];
#pragma unroll
      for (int mt = 0; mt < 4; ++mt)
        af[mt] = *(const bf16x8*)(As + (wm * 64 + mt * 16 + l15) * 128 + xo);
#pragma unroll
      for (int nt = 0; nt < 4; ++nt)
        bg[nt] = *(const bf16x8*)(Bs + (wn * 64 + nt * 16 + l15) * 128 + xo);
#pragma unroll
      for (int mt = 0; mt < 4; ++mt)
#pragma unroll
        for (int nt = 0; nt < 4; ++nt)
          acc[mt][nt] = __builtin_amdgcn_mfma_f32_16x16x32_bf16(
              af[mt], bg[nt], acc[mt][nt], 0, 0, 0);
    }
  }

  int p_base = row0 + wm * 64;
  int d_base = col0 + wn * 64;
#pragma unroll
  for (int mt = 0; mt < 4; ++mt) {
#pragma unroll
    for (int r = 0; r < 4; ++r) {
      int m2 = rowtok[p_base + mt * 16 + quad * 4 + r];
      int t = m2 & 0x3FFF;
      int dout = 128 << (m2 >> 14);
#pragma unroll
      for (int nt = 0; nt < 4; ++nt) {
        int d = d_base + nt * 16 + l15;
        float v = acc[mt][nt][r] + bias[d];
        out[(size_t)t * N + d] = (d < dout) ? v : 0.0f;
      }
    }
  }
}

extern "C" void kernel_launch(void* const* d_in, const int* in_sizes, int n_in,
                              void* d_out, int out_size, void* d_ws, size_t ws_size,
                              hipStream_t stream) {
  const float* x  = (const float*)d_in[0];
  const float* w1 = (const float*)d_in[1];
  const float* b1 = (const float*)d_in[2];
  const float* w2 = (const float*)d_in[3];
  const float* b2 = (const float*)d_in[4];
  const int*   tm = (const int*)d_in[5];
  float* out = (float*)d_out;

  char* ws = (char*)d_ws;
  int* meta = (int*)ws;                                     // 128 KB reserved
  unsigned short* xb  = (unsigned short*)(ws + 131072);     // 32 MB
  unsigned short* w1b = (unsigned short*)(ws + 33685504);   //  8 MB
  unsigned short* w2b = (unsigned short*)(ws + 42074112);   //  8 MB
  unsigned short* hb  = (unsigned short*)(ws + 50462720);   // 128 MB (176.125 MB total)

  sort_kernel<<<1, 1024, 0, stream>>>(tm, meta);
  prep_kernel<<<M_TOK + 8192, 256, 0, stream>>>(x, w1, w2, meta, xb, w1b, w2b);
  gemm1_kernel<<<dim3(M_TOK / 128, HID / 128), 256, 0, stream>>>(xb, w1b, b1, meta, hb);
  gemm2_kernel<<<1024, 256, 0, stream>>>(hb, w2b, b2, meta, out);
}

// Round 5
// 363.716 us; speedup vs baseline: 1.5108x; 1.0199x over previous
//
#include <hip/hip_runtime.h>
#include <hip/hip_bf16.h>

// NestedFeedForward: x[16384,1024] fp32, w1[4096,1024], b1[4096], w2[1024,4096],
// b2[1024], token_mask[16384] in [0,4).   d(t) = 128 << mask[t]
//   h = gelu_erf( mask_in(x) @ w1^T + b1 )   (hidden always full 4096)
//   y = mask_out( h @ w2^T + b2 )
// Round 4: gemm1 back to direct stores (R3 LDS epilogue was a measured
// regression: writes weren't the bottleneck), gemm1 grid high-K-first;
// gemm2 retiled to 64x128 (962 compute blocks ~3.8/CU vs 481 ~1.9/CU).

typedef __bf16 bf16x8 __attribute__((ext_vector_type(8)));
typedef float f32x4 __attribute__((ext_vector_type(4)));

#define M_TOK   16384
#define DIM     1024
#define HID     4096

// meta (ints at ws+0): [31] T, [64..191] kmax per 128-row gemm1 block,
// [256..2303] gemm2 map (compute blocks first, zero blocks after; 2048 = 256
// strips x 8 colblocks), [2560..18943] rowtok.
#define META_T     31
#define META_BLK   64
#define META_MAP   256
#define META_RT    2560

__device__ inline unsigned short f2bf(float f) {
  unsigned int u = __float_as_uint(f);
  u += 0x7fffu + ((u >> 16) & 1u);      // RNE; inputs finite
  return (unsigned short)(u >> 16);
}

// gelu with A&S 7.1.26 erf: abs err <= ~2.5e-5 (system absmax 0.0039 vs 0.0216)
__device__ inline float gelu_f(float v) {
  float z = fabsf(v) * 0.7071067811865475f;
  float t = __builtin_amdgcn_rcpf(fmaf(0.3275911f, z, 1.0f));
  float p = fmaf(t, 1.061405429f, -1.453152027f);
  p = fmaf(t, p, 1.421413741f);
  p = fmaf(t, p, -0.284496736f);
  p = fmaf(t, p, 0.254829592f);
  p = p * t;
  float E = __expf(-0.5f * v * v);
  float er = fmaf(-p, E, 1.0f);
  er = copysignf(er, v);
  return 0.5f * v * (1.0f + er);
}

__device__ inline void async_copy16(const void* g, void* s) {
  __builtin_amdgcn_global_load_lds(
      (const __attribute__((address_space(1))) unsigned int*)g,
      (__attribute__((address_space(3))) unsigned int*)s,
      16, 0, 0);
}

// Stage a ROWS x 64-col bf16 tile into LDS with XOR chunk swizzle (2-way
// aliasing on the b128 readbacks = free, m136).
template<int ROWS, int LDK>
__device__ inline void stage_tile(const unsigned short* __restrict__ g,
                                  int row0, int k0, char* lds) {
  const char* gbase = (const char*)g;
  int tid = threadIdx.x;
#pragma unroll
  for (int i = 0; i < ROWS / 32; ++i) {
    int q = i * 256 + tid;          // ROWS*8 chunks of 16B
    int r = q >> 3;                 // tile row
    int c = q & 7;                  // LDS chunk within row
    int gc = c ^ (r & 7);           // swizzled source chunk
    const void* gp = gbase + ((size_t)(row0 + r) * LDK + (size_t)k0 + gc * 8) * 2;
    async_copy16(gp, lds + (size_t)q * 16);
  }
}

// ---------------- fused sort + metadata (single block) ----------------
__global__ __launch_bounds__(1024) void sort_kernel(const int* __restrict__ tm,
                                                    int* __restrict__ meta) {
  __shared__ int cnt[1024][5];      // stride 5 dwords -> conflict-free
  __shared__ int sbase[5];
  __shared__ int cb[256];
  __shared__ int pfx[257];
  int tid = threadIdx.x;

  int c0 = 0, c1 = 0, c2 = 0, c3 = 0;
  unsigned int epack = 0;
  int4 tv[4];
#pragma unroll
  for (int j = 0; j < 4; ++j)
    tv[j] = *(const int4*)(tm + tid * 16 + j * 4);
#pragma unroll
  for (int j = 0; j < 4; ++j) {
    int e;
    e = tv[j].x; epack |= (unsigned)e << (2 * (4 * j + 0)); c0 += (e == 0); c1 += (e == 1); c2 += (e == 2); c3 += (e == 3);
    e = tv[j].y; epack |= (unsigned)e << (2 * (4 * j + 1)); c0 += (e == 0); c1 += (e == 1); c2 += (e == 2); c3 += (e == 3);
    e = tv[j].z; epack |= (unsigned)e << (2 * (4 * j + 2)); c0 += (e == 0); c1 += (e == 1); c2 += (e == 2); c3 += (e == 3);
    e = tv[j].w; epack |= (unsigned)e << (2 * (4 * j + 3)); c0 += (e == 0); c1 += (e == 1); c2 += (e == 2); c3 += (e == 3);
  }
  cnt[tid][0] = c0; cnt[tid][1] = c1; cnt[tid][2] = c2; cnt[tid][3] = c3;
  __syncthreads();
  for (int s = 1; s < 1024; s <<= 1) {
    int v0 = 0, v1 = 0, v2 = 0, v3 = 0;
    if (tid >= s) {
      v0 = cnt[tid - s][0]; v1 = cnt[tid - s][1];
      v2 = cnt[tid - s][2]; v3 = cnt[tid - s][3];
    }
    __syncthreads();
    cnt[tid][0] += v0; cnt[tid][1] += v1; cnt[tid][2] += v2; cnt[tid][3] += v3;
    __syncthreads();
  }
  if (tid == 0) {
    int b = 0;
#pragma unroll
    for (int e = 0; e < 4; ++e) { sbase[e] = b; b += cnt[1023][e]; }
    sbase[4] = b;
  }
  __syncthreads();
  int off0 = sbase[0] + cnt[tid][0] - c0;
  int off1 = sbase[1] + cnt[tid][1] - c1;
  int off2 = sbase[2] + cnt[tid][2] - c2;
  int off3 = sbase[3] + cnt[tid][3] - c3;
  int* rowtok = meta + META_RT;
#pragma unroll
  for (int j = 0; j < 16; ++j) {
    int e = (epack >> (2 * j)) & 3;
    int t = tid * 16 + j;
    int pos = (e == 0) ? off0++ : (e == 1) ? off1++ : (e == 2) ? off2++ : off3++;
    rowtok[pos] = t | (e << 14);
  }
  // strip-level (64-row) metadata for gemm2 + 128-row kmax for gemm1
  if (tid < 256) {
    int last = tid * 64 + 63;
    int e = (last >= sbase[1]) + (last >= sbase[2]) + (last >= sbase[3]);
    cb[tid] = 1 << e;                       // compute colblocks for this strip
    if (tid & 1) meta[META_BLK + (tid >> 1)] = 128 << e;   // 128-block kmax
  }
  __syncthreads();
  if (tid == 0) {
    int acc = 0;
    for (int j = 0; j < 256; ++j) { pfx[j] = acc; acc += cb[j]; }
    pfx[256] = acc;
    meta[META_T] = acc;
  }
  __syncthreads();
  if (tid < 256) {
    int n = cb[tid];
    int p = pfx[tid];
    int* map = meta + META_MAP;
    for (int c = 0; c < n; ++c) map[p + c] = tid * 8 + c;
    int zp = pfx[256] + 8 * tid - pfx[tid];          // zeros before this strip
    for (int c = n; c < 8; ++c) map[zp + (c - n)] = tid * 8 + c;
  }
}

// ---------------- fused prep: cvt_x (permuted gather) + w1/w2 -> bf16 ------
__global__ void prep_kernel(const float* __restrict__ x,
                            const float* __restrict__ w1,
                            const float* __restrict__ w2,
                            const int* __restrict__ meta,
                            unsigned short* __restrict__ xb,
                            unsigned short* __restrict__ w1b,
                            unsigned short* __restrict__ w2b) {
  int b = blockIdx.x;
  int tid = threadIdx.x;
  if (b < M_TOK) {
    int mt = meta[META_RT + b];
    int t = mt & 0x3FFF;
    int din = 128 << (mt >> 14);
    int d = tid * 4;
    float4 v = *(const float4*)(x + (size_t)t * DIM + d);
    ushort4 o;
    if (d < din) {                  // din multiple of 128 -> float4-uniform
      o.x = f2bf(v.x); o.y = f2bf(v.y); o.z = f2bf(v.z); o.w = f2bf(v.w);
    } else {
      o.x = 0; o.y = 0; o.z = 0; o.w = 0;
    }
    *(ushort4*)(xb + (size_t)b * DIM + d) = o;
  } else {
    size_t i = (size_t)(b - M_TOK) * 1024 + tid * 4;   // 0 .. 8388607
    const float* src;
    unsigned short* dst;
    if (i < (size_t)HID * DIM) { src = w1; dst = w1b; }
    else { src = w2 - (size_t)HID * DIM; dst = w2b - (size_t)HID * DIM; }
    float4 v = *(const float4*)(src + i);
    ushort4 o;
    o.x = f2bf(v.x); o.y = f2bf(v.y); o.z = f2bf(v.z); o.w = f2bf(v.w);
    *(ushort4*)(dst + i) = o;
  }
}

// ---- GEMM1: hb[pos,f] = gelu( xb[pos,:] . w1b[f,:] + b1[f] ), bf16 out ----
// Flat grid, high-K rowblocks first (rowblk = 127 - b/32) for load balance;
// colblock fast-varying so consecutive blocks share the A-tile in L2.
__global__ __launch_bounds__(256) void gemm1_kernel(
    const unsigned short* __restrict__ A,   // xb [16384,1024] bf16 (permuted)
    const unsigned short* __restrict__ B,   // w1b [4096,1024] bf16
    const float* __restrict__ bias,         // b1 [4096]
    const int* __restrict__ meta,
    unsigned short* __restrict__ H)         // hb [16384,4096] bf16 (permuted)
{
  constexpr int K = DIM, N = HID;
  __shared__ char smem[32768];
  char* As = smem;
  char* Bs = smem + 16384;
  int tid = threadIdx.x;
  int lane = tid & 63, quad = lane >> 4, l15 = lane & 15;
  int wave = tid >> 6, wm = wave & 1, wn = wave >> 1;
  int rowblk = 127 - (blockIdx.x >> 5);
  int row0 = rowblk * 128, col0 = (blockIdx.x & 31) * 128;
  int kmax = meta[META_BLK + rowblk];

  int chb = (quad ^ (l15 & 7)) << 4;        // staging swizzle base

  f32x4 acc[4][4] = {};

  for (int k0 = 0; k0 < kmax; k0 += 64) {
    __syncthreads();
    stage_tile<128, K>(A, row0, k0, As);
    stage_tile<128, K>(B, col0, k0, Bs);
    __syncthreads();
#pragma unroll
    for (int kk = 0; kk < 2; ++kk) {
      int xo = chb ^ (kk << 6);
      bf16x8 af[4], bg[4];
#pragma unroll
      for (int mt = 0; mt < 4; ++mt)
        af[mt] = *(const bf16x8*)(As + (wm * 64 + mt * 16 + l15) * 128 + xo);
#pragma unroll
      for (int nt = 0; nt < 4; ++nt)
        bg[nt] = *(const bf16x8*)(Bs + (wn * 64 + nt * 16 + l15) * 128 + xo);
#pragma unroll
      for (int mt = 0; mt < 4; ++mt)
#pragma unroll
        for (int nt = 0; nt < 4; ++nt)
          acc[mt][nt] = __builtin_amdgcn_mfma_f32_16x16x32_bf16(
              af[mt], bg[nt], acc[mt][nt], 0, 0, 0);
    }
  }

  // Direct-store epilogue (measured faster than LDS round-trip: 150 vs 164 us)
  int t_base = row0 + wm * 64;
  int f_base = col0 + wn * 64;
#pragma unroll
  for (int nt = 0; nt < 4; ++nt) {
    int f = f_base + nt * 16 + l15;
    float bv = bias[f];
#pragma unroll
    for (int mt = 0; mt < 4; ++mt) {
#pragma unroll
      for (int r = 0; r < 4; ++r) {
        int t = t_base + mt * 16 + quad * 4 + r;
        float v = gelu_f(acc[mt][nt][r] + bv);
        H[(size_t)t * N + f] = f2bf(v);
      }
    }
  }
}

// ---- GEMM2: 64x128 tiles. Compute blocks b<T; zero blocks b>=T ----
__global__ __launch_bounds__(256) void gemm2_kernel(
    const unsigned short* __restrict__ A,   // hb [16384,4096] bf16 (permuted)
    const unsigned short* __restrict__ B,   // w2b [1024,4096] bf16
    const float* __restrict__ bias,         // b2 [1024]
    const int* __restrict__ meta,
    float* __restrict__ out)                // [16384,1024] fp32
{
  constexpr int K = HID, N = DIM;
  int T = meta[META_T];
  int b = blockIdx.x;
  int mp = meta[META_MAP + b];
  int row0 = (mp >> 3) * 64, col0 = (mp & 7) * 128;
  const int* rowtok = meta + META_RT;
  int tid = threadIdx.x;

  if (b >= T) {
    // every row in this strip has dout <= col0: coalesced zeros
    float4 z = make_float4(0.f, 0.f, 0.f, 0.f);
#pragma unroll
    for (int i = 0; i < 8; ++i) {
      int idx = i * 256 + tid;              // 2048 float4 = 64x128 tile
      int r = idx >> 5;
      int col = (idx & 31) * 4;
      int t = rowtok[row0 + r] & 0x3FFF;
      *(float4*)(out + (size_t)t * N + col0 + col) = z;
    }
    return;
  }

  __shared__ char smem[24576];
  char* As = smem;                          // 8 KB (64x64)
  char* Bs = smem + 8192;                   // 16 KB (128x64)
  int lane = tid & 63, quad = lane >> 4, l15 = lane & 15;
  int wave = tid >> 6, wm = wave & 1, wn = wave >> 1;
  int chb = (quad ^ (l15 & 7)) << 4;

  f32x4 acc[2][4] = {};

  for (int k0 = 0; k0 < K; k0 += 64) {
    __syncthreads();
    stage_tile<64, K>(A, row0, k0, As);
    stage_tile<128, K>(B, col0, k0, Bs);
    __syncthreads();
#pragma unroll
    for (int kk = 0; kk < 2; ++kk) {
      int xo = chb ^ (kk << 6);
      bf16x8 af[2], bg[4];
#pragma unroll
      for (int mt = 0; mt < 2; ++mt)
        af[mt] = *(const bf16x8*)(As + (wm * 32 + mt * 16 + l15) * 128 + xo);
#pragma unroll
      for (int nt = 0; nt < 4; ++nt)
        bg[nt] = *(const bf16x8*)(Bs + (wn * 64 + nt * 16 + l15) * 128 + xo);
#pragma unroll
      for (int mt = 0; mt < 2; ++mt)
#pragma unroll
        for (int nt = 0; nt < 4; ++nt)
          acc[mt][nt] = __builtin_amdgcn_mfma_f32_16x16x32_bf16(
              af[mt], bg[nt], acc[mt][nt], 0, 0, 0);
    }
  }

  int p_base = row0 + wm * 32;
  int d_base = col0 + wn * 64;
#pragma unroll
  for (int mt = 0; mt < 2; ++mt) {
#pragma unroll
    for (int r = 0; r < 4; ++r) {
      int m2 = rowtok[p_base + mt * 16 + quad * 4 + r];
      int t = m2 & 0x3FFF;
      int dout = 128 << (m2 >> 14);
#pragma unroll
      for (int nt = 0; nt < 4; ++nt) {
        int d = d_base + nt * 16 + l15;
        float v = acc[mt][nt][r] + bias[d];
        out[(size_t)t * N + d] = (d < dout) ? v : 0.0f;
      }
    }
  }
}

extern "C" void kernel_launch(void* const* d_in, const int* in_sizes, int n_in,
                              void* d_out, int out_size, void* d_ws, size_t ws_size,
                              hipStream_t stream) {
  const float* x  = (const float*)d_in[0];
  const float* w1 = (const float*)d_in[1];
  const float* b1 = (const float*)d_in[2];
  const float* w2 = (const float*)d_in[3];
  const float* b2 = (const float*)d_in[4];
  const int*   tm = (const int*)d_in[5];
  float* out = (float*)d_out;

  char* ws = (char*)d_ws;
  int* meta = (int*)ws;                                     // 128 KB reserved
  unsigned short* xb  = (unsigned short*)(ws + 131072);     // 32 MB
  unsigned short* w1b = (unsigned short*)(ws + 33685504);   //  8 MB
  unsigned short* w2b = (unsigned short*)(ws + 42074112);   //  8 MB
  unsigned short* hb  = (unsigned short*)(ws + 50462720);   // 128 MB (176.125 MB)

  sort_kernel<<<1, 1024, 0, stream>>>(tm, meta);
  prep_kernel<<<M_TOK + 8192, 256, 0, stream>>>(x, w1, w2, meta, xb, w1b, w2b);
  gemm1_kernel<<<4096, 256, 0, stream>>>(xb, w1b, b1, meta, hb);
  gemm2_kernel<<<2048, 256, 0, stream>>>(hb, w2b, b2, meta, out);
}